// Round 2
// baseline (365.816 us; speedup 1.0000x reference)
//
#include <hip/hip_runtime.h>
#include <hip/hip_bf16.h>

// QuantizedEmbedding: out[b,s,d] = (nib(packed[idx[b,s], d/2], d&1) - zeros[idx,g]) * scales[idx,g]
// D=1024, GROUP=64 -> 16 groups/row; packed has D/2=512 entries per row.
//
// HARNESS NOTE: all integer inputs arrive as int32 (one element per int32),
// so the uint8 packed table is delivered as int32[VOCAB*512] — row stride
// 2048 BYTES. Reading it as uint8 was R1's bug (absmax ~= full value range).
//
// Memory-bound: 134 MB f32 output write + ~60 MB gathered packed reads.
// Each thread: 4 output elements = 1 int2 packed load (2 byte-values ->
// 4 nibbles) + 1 scale + 1 zero + 1 coalesced float4 store.

#define D_DIM 1024
#define ROW_I32 512          // D/2 int32 entries per packed row
#define NGROUPS 16           // D/GROUP

__global__ __launch_bounds__(256) void qembed_kernel(
        const int* __restrict__ indices,
        const int* __restrict__ packed,    // int32 per original uint8 element
        const float* __restrict__ scales,
        const float* __restrict__ zeros,
        float* __restrict__ out,
        int n_rows) {
    int i = blockIdx.x * blockDim.x + threadIdx.x;   // one thread -> 4 output elems
    int row = i >> 8;                                 // 256 threads per row (1024/4)
    if (row >= n_rows) return;
    int off4 = (i & 255) << 2;                        // element offset within row [0,1024)

    int idx = indices[row];

    // two packed byte-values (each stored as int32) -> 4 nibbles, low nibble first
    int2 pk = *(const int2*)(packed + (size_t)idx * ROW_I32 + (off4 >> 1));

    int g = off4 >> 6;                                // group index (GROUP=64)
    float s = scales[idx * NGROUPS + g];
    float z = zeros[idx * NGROUPS + g];

    float4 o;
    o.x = ((float)( pk.x & 0xF) - z) * s;
    o.y = ((float)( pk.x >> 4 ) - z) * s;             // byte value 0..255 -> high nibble
    o.z = ((float)( pk.y & 0xF) - z) * s;
    o.w = ((float)( pk.y >> 4 ) - z) * s;

    *(float4*)(out + (size_t)row * D_DIM + off4) = o;
}

extern "C" void kernel_launch(void* const* d_in, const int* in_sizes, int n_in,
                              void* d_out, int out_size, void* d_ws, size_t ws_size,
                              hipStream_t stream) {
    const int* indices = (const int*)d_in[0];
    const int* packed  = (const int*)d_in[1];
    const float* scales = (const float*)d_in[2];
    const float* zeros  = (const float*)d_in[3];
    float* out          = (float*)d_out;

    int n_rows = in_sizes[0];                 // B*S = 32768
    int block = 256;
    int grid = n_rows;                        // 256 threads x 4 elems = 1024 = one row per block

    qembed_kernel<<<grid, block, 0, stream>>>(indices, packed, scales, zeros, out, n_rows);
}

// Round 4
// 362.010 us; speedup vs baseline: 1.0105x; 1.0105x over previous
//
#include <hip/hip_runtime.h>
#include <hip/hip_bf16.h>

// QuantizedEmbedding: out[b,s,d] = (nib(packed[idx[b,s], d/2], d&1) - zeros[idx,g]) * scales[idx,g]
// D=1024, GROUP=64 -> 16 groups/row; packed has D/2=512 entries per row.
//
// HARNESS NOTE: all integer inputs arrive as int32 (one element per int32),
// so the uint8 packed table is delivered as int32[VOCAB*512] — row stride
// 2048 BYTES (262 MB table, just over the 256 MB L3).
//
// Memory-bound: 134 MB f32 output write (once, never re-read) + ~60 MB
// unique gathered packed reads. R4: nontemporal output stores (native clang
// ext_vector_type — __builtin_nontemporal_store rejects HIP's float4 class)
// so streaming writes don't evict the gather table from L2/L3.

#define D_DIM 1024
#define ROW_I32 512          // D/2 int32 entries per packed row
#define NGROUPS 16           // D/GROUP

typedef float vfloat4 __attribute__((ext_vector_type(4)));
typedef int   vint2   __attribute__((ext_vector_type(2)));

__global__ __launch_bounds__(256) void qembed_kernel(
        const int* __restrict__ indices,
        const int* __restrict__ packed,    // int32 per original uint8 element
        const float* __restrict__ scales,
        const float* __restrict__ zeros,
        float* __restrict__ out,
        int n_rows) {
    int i = blockIdx.x * blockDim.x + threadIdx.x;   // one thread -> 4 output elems
    int row = i >> 8;                                 // 256 threads per row (1024/4)
    if (row >= n_rows) return;
    int off4 = (i & 255) << 2;                        // element offset within row [0,1024)

    int idx = indices[row];

    // two packed byte-values (each stored as int32) -> 4 nibbles, low nibble first
    vint2 pk = *(const vint2*)(packed + (size_t)idx * ROW_I32 + (off4 >> 1));

    int g = off4 >> 6;                                // group index (GROUP=64)
    float s = scales[idx * NGROUPS + g];
    float z = zeros[idx * NGROUPS + g];

    vfloat4 o;
    o.x = ((float)( pk.x & 0xF) - z) * s;
    o.y = ((float)( pk.x >> 4 ) - z) * s;             // byte value 0..255 -> high nibble
    o.z = ((float)( pk.y & 0xF) - z) * s;
    o.w = ((float)( pk.y >> 4 ) - z) * s;

    // streaming store: output is write-once, keep it out of L2/L3 so the
    // 262 MB gather table stays resident
    __builtin_nontemporal_store(o, (vfloat4*)(out + (size_t)row * D_DIM + off4));
}

extern "C" void kernel_launch(void* const* d_in, const int* in_sizes, int n_in,
                              void* d_out, int out_size, void* d_ws, size_t ws_size,
                              hipStream_t stream) {
    const int* indices = (const int*)d_in[0];
    const int* packed  = (const int*)d_in[1];
    const float* scales = (const float*)d_in[2];
    const float* zeros  = (const float*)d_in[3];
    float* out          = (float*)d_out;

    int n_rows = in_sizes[0];                 // B*S = 32768
    int block = 256;
    int grid = n_rows;                        // 256 threads x 4 elems = one row per block

    qembed_kernel<<<grid, block, 0, stream>>>(indices, packed, scales, zeros, out, n_rows);
}

// Round 5
// 361.978 us; speedup vs baseline: 1.0106x; 1.0001x over previous
//
#include <hip/hip_runtime.h>
#include <hip/hip_bf16.h>

// QuantizedEmbedding: out[b,s,d] = (nib(packed[idx[b,s], d/2], d&1) - zeros[idx,g]) * scales[idx,g]
// D=1024, GROUP=64 -> 16 groups/row; packed has D/2=512 entries per row.
//
// HARNESS NOTE: all integer inputs arrive as int32 (one element per int32),
// so the uint8 packed table is delivered as int32[VOCAB*512] — row stride
// 2048 BYTES (262 MB table, just over the 256 MB L3).
//
// R5: 8 elems/thread (128 threads/row, 2 rows/block) — halves wave count,
// amortizes the idx load + addressing. Thread t of a row covers elems
// [4t,4t+4) and [512+4t,512+4t+4): every load/store instruction stays fully
// lane-dense (adjacent lanes -> adjacent 16B), which matters for the
// nontemporal stores (no reliance on L2 write-combining).
// Output is write-once -> nt stores keep L2/L3 capacity for the gather table.

#define D_DIM 1024
#define ROW_I32 512          // D/2 int32 entries per packed row
#define NGROUPS 16           // D/GROUP

typedef float vfloat4 __attribute__((ext_vector_type(4)));
typedef int   vint2   __attribute__((ext_vector_type(2)));

__global__ __launch_bounds__(256) void qembed_kernel(
        const int* __restrict__ indices,
        const int* __restrict__ packed,    // int32 per original uint8 element
        const float* __restrict__ scales,
        const float* __restrict__ zeros,
        float* __restrict__ out,
        int n_rows) {
    int t = blockIdx.x * blockDim.x + threadIdx.x;
    int row = t >> 7;                      // 128 threads per row
    if (row >= n_rows) return;
    int lane = t & 127;

    int idx = indices[row];
    const int* prow = packed + (size_t)idx * ROW_I32;

    // two packed segments: elems [4*lane, 4*lane+4) and [512+4*lane, ...)
    vint2 p0 = *(const vint2*)(prow + 2 * lane);
    vint2 p1 = *(const vint2*)(prow + (ROW_I32 / 2) + 2 * lane);

    int g0 = lane >> 4;                    // group of first segment (GROUP=64)
    int g1 = (NGROUPS / 2) + g0;           // group of second segment
    float s0 = scales[idx * NGROUPS + g0];
    float z0 = zeros [idx * NGROUPS + g0];
    float s1 = scales[idx * NGROUPS + g1];
    float z1 = zeros [idx * NGROUPS + g1];

    vfloat4 o0, o1;
    o0.x = ((float)(p0.x & 0xF) - z0) * s0;
    o0.y = ((float)(p0.x >> 4 ) - z0) * s0;
    o0.z = ((float)(p0.y & 0xF) - z0) * s0;
    o0.w = ((float)(p0.y >> 4 ) - z0) * s0;
    o1.x = ((float)(p1.x & 0xF) - z1) * s1;
    o1.y = ((float)(p1.x >> 4 ) - z1) * s1;
    o1.z = ((float)(p1.y & 0xF) - z1) * s1;
    o1.w = ((float)(p1.y >> 4 ) - z1) * s1;

    float* orow = out + (size_t)row * D_DIM;
    __builtin_nontemporal_store(o0, (vfloat4*)(orow + 4 * lane));
    __builtin_nontemporal_store(o1, (vfloat4*)(orow + (D_DIM / 2) + 4 * lane));
}

extern "C" void kernel_launch(void* const* d_in, const int* in_sizes, int n_in,
                              void* d_out, int out_size, void* d_ws, size_t ws_size,
                              hipStream_t stream) {
    const int* indices = (const int*)d_in[0];
    const int* packed  = (const int*)d_in[1];
    const float* scales = (const float*)d_in[2];
    const float* zeros  = (const float*)d_in[3];
    float* out          = (float*)d_out;

    int n_rows = in_sizes[0];                 // B*S = 32768
    int block = 256;                          // 2 rows per block
    int grid = (n_rows * 128 + block - 1) / block;

    qembed_kernel<<<grid, block, 0, stream>>>(indices, packed, scales, zeros, out, n_rows);
}